// Round 1
// baseline (220.712 us; speedup 1.0000x reference)
//
#include <hip/hip_runtime.h>

// De-emphasis IIR: y[n] = x[n] + C*y[n-1] per row, rows of length 480000.
// Strategy: affine-map scan. Per-thread local scan of 16 elems (registers),
// wave-level shfl affine scan of segment totals, LDS scan across the 16
// waves of the block. Cross-block carry handled by a 1024-element halo:
// 0.97^1024 ~ 2.8e-14, so truncation error is below fp32 noise.

#define COEFF 0.97f
#define ROW_LEN 480000
#define SEG 16                         // elements per thread
#define BLOCK 1024                     // threads per block (16 waves)
#define HALO_SEGS 64                   // halo = one wave's worth of segments
#define HALO (HALO_SEGS * SEG)         // 1024 elements
#define SPAN (BLOCK * SEG)             // 16384 elements scanned per block
#define OUT_PER_BLOCK (SPAN - HALO)    // 15360 elements written per block
#define BLOCKS_PER_ROW ((ROW_LEN + OUT_PER_BLOCK - 1) / OUT_PER_BLOCK)  // 32

constexpr float fpow(float b, int n) {
    float r = 1.0f;
    for (int i = 0; i < n; ++i) r *= b;
    return r;
}
constexpr float C16   = fpow(COEFF, SEG);    // per-segment decay
constexpr float C1024 = fpow(COEFF, HALO);   // per-wave decay (~2.8e-14)

__global__ __launch_bounds__(BLOCK) void deemph_kernel(const float* __restrict__ x,
                                                       float* __restrict__ y) {
    const int row  = blockIdx.y;
    const int blk  = blockIdx.x;
    const int t    = threadIdx.x;
    const int lane = t & 63;
    const int wave = t >> 6;

    const long long row_base  = (long long)row * ROW_LEN;
    const int out_start = blk * OUT_PER_BLOCK;
    const int seg_start = out_start - HALO + t * SEG;  // within-row, may be <0 or >=ROW_LEN

    // ---- load 16 elements (zero-fill outside the row: exact at row start,
    //      don't-care past row end) ----
    float l[SEG];
    const bool in_row = (seg_start >= 0) && (seg_start < ROW_LEN);
    if (in_row) {
        const float4* p = (const float4*)(x + row_base + seg_start);
        #pragma unroll
        for (int q = 0; q < SEG / 4; ++q) {
            float4 v = p[q];
            l[4*q+0] = v.x; l[4*q+1] = v.y; l[4*q+2] = v.z; l[4*q+3] = v.w;
        }
    } else {
        #pragma unroll
        for (int i = 0; i < SEG; ++i) l[i] = 0.0f;
    }

    // ---- local inclusive scan with zero carry-in ----
    #pragma unroll
    for (int i = 1; i < SEG; ++i) l[i] = fmaf(COEFF, l[i-1], l[i]);

    // ---- wave-level inclusive affine scan over segment maps (A,B):
    //      combine(left,right) = (A_l*A_r, A_r*B_l + B_r) ----
    float A = C16;
    float B = l[SEG-1];
    #pragma unroll
    for (int d = 1; d < 64; d <<= 1) {
        float Ap = __shfl_up(A, d);
        float Bp = __shfl_up(B, d);
        if (lane >= d) { B = fmaf(A, Bp, B); A *= Ap; }
    }
    // exclusive (carry into this thread from earlier threads in the wave)
    float Aex = __shfl_up(A, 1);
    float Bex = __shfl_up(B, 1);
    if (lane == 0) { Aex = 1.0f; Bex = 0.0f; }

    // ---- cross-wave: scan the 16 wave totals via LDS ----
    __shared__ float wsum[BLOCK / 64];
    if (lane == 63) wsum[wave] = B;   // inclusive wave total
    __syncthreads();
    float Cw = 0.0f;                  // carry into this wave
    for (int v = 0; v < wave; ++v) Cw = fmaf(C1024, Cw, wsum[v]);

    // total carry into this thread's segment
    const float K = fmaf(Aex, Cw, Bex);

    // ---- apply carry: y_i = l_i + c^(i+1) * K ----
    float kp = COEFF * K;
    #pragma unroll
    for (int i = 0; i < SEG; ++i) { l[i] += kp; kp *= COEFF; }

    // ---- store (only non-halo, in-row segments) ----
    if (t >= HALO_SEGS && seg_start < ROW_LEN) {
        float4* q = (float4*)(y + row_base + seg_start);
        #pragma unroll
        for (int j = 0; j < SEG / 4; ++j) {
            float4 v;
            v.x = l[4*j+0]; v.y = l[4*j+1]; v.z = l[4*j+2]; v.w = l[4*j+3];
            q[j] = v;
        }
    }
}

extern "C" void kernel_launch(void* const* d_in, const int* in_sizes, int n_in,
                              void* d_out, int out_size, void* d_ws, size_t ws_size,
                              hipStream_t stream) {
    (void)n_in; (void)d_ws; (void)ws_size; (void)out_size;
    const float* x = (const float*)d_in[0];
    float* y = (float*)d_out;
    const int n_rows = in_sizes[0] / ROW_LEN;  // 64 for (32,2,480000)
    dim3 grid(BLOCKS_PER_ROW, n_rows);
    deemph_kernel<<<grid, BLOCK, 0, stream>>>(x, y);
}